// Round 7
// baseline (40.232 us; speedup 1.0000x reference)
//
#include <hip/hip_runtime.h>
#include <hip/hip_bf16.h>

// Problem constants
#define BB 64
#define LL 4096
#define CC 16
#define PL 128
#define PC 8
#define NPP 64
#define DD 64
#define TSTEP 0.01f

#define PPB 32                      // patches per block (MFMA M)
#define KSPLIT 8                    // lt-range split across blocks
#define LT_PER (PL / KSPLIT)        // 16 lt steps per block
#define NT_MAIN 256                 // 4 waves = 2 ns-slices x 2 kk-halves
#define NMB (BB * (NPP / PPB))      // 128 M-tiles

#define FRAG_U32 (PL * 8 * 256)                      // 1 MB of W3 bf16 frags
#define PART_FLT (KSPLIT * NMB * 2 * 64 * 16)        // 8 MB of f32 partials
#define SPLIT_STRIDE (NMB * 2 * 64 * 16)             // floats per split

typedef float f32x4  __attribute__((ext_vector_type(4)));
typedef float f32x16 __attribute__((ext_vector_type(16)));
typedef int   i32x4  __attribute__((ext_vector_type(4)));
typedef unsigned int u32;

__device__ __forceinline__ float silu_f(float z) {      // z * rcp(1+exp(-z))
    return z * __builtin_amdgcn_rcpf(1.0f + __expf(-z));
}
__device__ __forceinline__ u32 pack_bf16(float lo, float hi) {
    __hip_bfloat162 p = __float22bfloat162_rn(float2{lo, hi});
    u32 r;
    __builtin_memcpy(&r, &p, 4);
    return r;
}

// ---- W3 (8192x64 f32) -> bf16 frags for mfma_32x32x16, in ws (1 MB) ----
// frag m = ltg*8 + kk*4 + ksub*2 + ns ; lane holds W3[k0 + 2j(+1)][ns*32 + (l&31)]
__global__ __launch_bounds__(256) void w3_prep(const float* __restrict__ W3,
                                               u32* __restrict__ wsf) {
    const int tid  = blockIdx.x * 256 + threadIdx.x;    // 65536 threads
    const int lane = tid & 63;
    const int m    = tid >> 6;                          // 0..1023
    const int ns   = m & 1;
    const int ksub = (m >> 1) & 1;
    const int kk   = (m >> 2) & 1;
    const int ltg  = m >> 3;
    const int k0   = ltg * 64 + kk * 32 + ksub * 16 + ((lane >> 5) << 3);
    const int col  = (ns << 5) + (lane & 31);
    u32 q[4];
    #pragma unroll
    for (int jj = 0; jj < 4; ++jj)
        q[jj] = pack_bf16(W3[(size_t)(k0 + 2 * jj)     * DD + col],
                          W3[(size_t)(k0 + 2 * jj + 1) * DD + col]);
    i32x4 v; v.x = (int)q[0]; v.y = (int)q[1]; v.z = (int)q[2]; v.w = (int)q[3];
    *(i32x4*)(wsf + (size_t)m * 256 + (lane << 2)) = v;
}

// ---------------------------- fused main kernel ----------------------------
// NOTE: no min-waves hint — round 4 showed __launch_bounds__(...,8) spills the
// hoisted W1 state to scratch (WRITE_SIZE 4->90 MB, VALUBusy 49->21%).
__global__ __launch_bounds__(NT_MAIN) void htfe_main(
    const float* __restrict__ x, const int* __restrict__ start_L,
    const int* __restrict__ idx_C, const float* __restrict__ W1,
    const float* __restrict__ b1, const u32* __restrict__ wsf,
    float* __restrict__ part)
{
    __shared__ __align__(16) u32   xq[LT_PER][PPB][4];   // 8 KB bf16 gathered x
    __shared__ __align__(16) u32   hbuf[2][PPB][32];     // 2x4 KB bf16 h, swizzled
    __shared__ __align__(16) float redbuf[2][64][16];    // 8 KB kk-reduction
    __shared__ int sStart[PPB];
    __shared__ int sCi[PPB][PC];

    const int t    = threadIdx.x;
    const int lane = t & 63;
    const int w    = t >> 6;
    const int ns   = w & 1;                  // N-slice (32 d_out)
    const int kk   = w >> 1;                 // K-half (32 of 64 k per lt)

    // XCD grouping: all 8 splits of one mb share mb%8 -> same XCD (L2 reuse)
    const int mb    = blockIdx.x & (NMB - 1);
    const int split = blockIdx.x >> 7;
    const int b     = mb >> 1;
    const int p0    = (mb & 1) * PPB;
    const int lt0   = split * LT_PER;

    if (t < PPB) sStart[t] = start_L[b * NPP + p0 + t];
    if (t < PPB * PC) {
        const int pp = t >> 3, c = t & 7;
        sCi[pp][c] = idx_C[(size_t)((b * NPP + p0 + pp) << 3) + c];
    }
    __syncthreads();

    // ----- per-lane hoisted W1 slice + folded constant bias (2 patches) -----
    const int pA  = lane >> 2;                      // phase-A patch row 1
    const int pB2 = pA + 16;                        // phase-A patch row 2
    const int d0  = (w << 4) + ((lane & 3) << 2);   // 4 d-columns per thread
    float w1x[PC][4], w1t[4], cbA[4], cbB[4];
    {
        const f32x4 vt = *(const f32x4*)(W1 + PC * DD + d0);
        const f32x4 vb = *(const f32x4*)(b1 + d0);
        const float stA = (float)sStart[pA]  * TSTEP;   // start never wraps
        const float stB = (float)sStart[pB2] * TSTEP;
        #pragma unroll
        for (int j = 0; j < 4; ++j) {
            w1t[j] = vt[j];
            cbA[j] = vb[j] + stA * vt[j];
            cbB[j] = vb[j] + stB * vt[j];
        }
        #pragma unroll
        for (int c = 0; c < PC; ++c) {
            const f32x4 vx = *(const f32x4*)(W1 + c * DD + d0);
            const f32x4 vc = *(const f32x4*)(W1 + (PC + 1 + c) * DD + d0);
            const float cfA = (float)sCi[pA][c];
            const float cfB = (float)sCi[pB2][c];
            #pragma unroll
            for (int j = 0; j < 4; ++j) {
                w1x[c][j] = vx[j];
                cbA[j] += cfA * vc[j];
                cbB[j] += cfB * vc[j];
            }
        }
    }

    // ----- gather + bf16-pack all x values for this block's lt range -----
    #pragma unroll
    for (int uu = 0; uu < 2; ++uu) {
        const int u  = t * 2 + uu;            // 512 (lt,p) units
        const int lt = u >> 5;
        const int pp = u & 31;
        const float* xrow = x + ((size_t)b * LL + (size_t)(sStart[pp] + lt0 + lt)) * CC;
        u32 q[4];
        #pragma unroll
        for (int c2 = 0; c2 < 4; ++c2)
            q[c2] = pack_bf16(xrow[sCi[pp][2 * c2]], xrow[sCi[pp][2 * c2 + 1]]);
        i32x4 v; v.x = (int)q[0]; v.y = (int)q[1]; v.z = (int)q[2]; v.w = (int)q[3];
        *(i32x4*)&xq[lt][pp][0] = v;
    }
    __syncthreads();

    // swizzled h addresses: stored col byte = colbyte ^ ((row&7)<<4)
    const int wrA = (pA << 7) + (((w << 5) + ((lane & 3) << 3)) ^ ((pA & 7) << 4));
    const int aRow = (lane & 31) << 7;
    const int aSwz = (lane & 7) << 4;
    const int cb0  = (kk << 6) + ((lane >> 5) << 4);
    const int aOff0 = aRow + (cb0 ^ aSwz);
    const int aOff1 = aRow + ((cb0 + 32) ^ aSwz);

    f32x16 acc = {};
    const u32* bsrc = wsf + ((size_t)lt0 * 8 + kk * 4 + ns) * 256 + (lane << 2);

    for (int lt = 0; lt < LT_PER; ++lt) {
        const int cur = lt & 1;

        // ---- B-fragments first (global/L2, long latency) ----
        const i32x4 bf0 = *(const i32x4*)(bsrc);
        const i32x4 bf1 = *(const i32x4*)(bsrc + 512);   // ksub=1 frag
        bsrc += 2048;

        // ---- phase A: 2 patches x 4 d per thread, all-register ----
        const float tl = (float)(lt0 + lt) * TSTEP;
        const i32x4 qa = *(const i32x4*)&xq[lt][pA][0];
        const i32x4 qb = *(const i32x4*)&xq[lt][pB2][0];
        float aA[4], aB[4];
        #pragma unroll
        for (int j = 0; j < 4; ++j) {
            aA[j] = cbA[j] + tl * w1t[j];
            aB[j] = cbB[j] + tl * w1t[j];
        }
        #pragma unroll
        for (int c2 = 0; c2 < 4; ++c2) {
            const u32 ua = (u32)qa[c2], ub = (u32)qb[c2];
            const float xa0 = __uint_as_float(ua << 16);
            const float xa1 = __uint_as_float(ua & 0xffff0000u);
            const float xb0 = __uint_as_float(ub << 16);
            const float xb1 = __uint_as_float(ub & 0xffff0000u);
            #pragma unroll
            for (int j = 0; j < 4; ++j) {
                aA[j] += xa0 * w1x[2 * c2][j];
                aA[j] += xa1 * w1x[2 * c2 + 1][j];
                aB[j] += xb0 * w1x[2 * c2][j];
                aB[j] += xb1 * w1x[2 * c2 + 1][j];
            }
        }
        char* hb = (char*)&hbuf[cur][0][0];
        *(uint2*)(hb + wrA) =
            make_uint2(pack_bf16(silu_f(aA[0]), silu_f(aA[1])),
                       pack_bf16(silu_f(aA[2]), silu_f(aA[3])));
        *(uint2*)(hb + wrA + 2048) =
            make_uint2(pack_bf16(silu_f(aB[0]), silu_f(aB[1])),
                       pack_bf16(silu_f(aB[2]), silu_f(aB[3])));

        __syncthreads();   // h tile ready (double-buffered -> 1 barrier per lt)

        // ---- phase B: A-frags from swizzled LDS, 2 MFMAs (K=32 half) ----
        const i32x4 af0 = *(const i32x4*)(hb + aOff0);
        const i32x4 af1 = *(const i32x4*)(hb + aOff1);
        asm("v_mfma_f32_32x32x16_bf16 %0, %1, %2, %0" : "+v"(acc) : "v"(af0), "v"(bf0));
        asm("v_mfma_f32_32x32x16_bf16 %0, %1, %2, %0" : "+v"(acc) : "v"(af1), "v"(bf1));
    }

    asm volatile("s_nop 7\ns_nop 7\ns_nop 7" ::);  // MFMA-write -> read hazard
    // ---- in-block kk reduction, then one coalesced partial store ----
    if (kk) {
        #pragma unroll
        for (int r4 = 0; r4 < 4; ++r4) {
            f32x4 v;
            v.x = acc[r4 * 4 + 0]; v.y = acc[r4 * 4 + 1];
            v.z = acc[r4 * 4 + 2]; v.w = acc[r4 * 4 + 3];
            *(f32x4*)&redbuf[ns][lane][r4 * 4] = v;
        }
    }
    __syncthreads();
    if (!kk) {
        float* pdst = part + ((((size_t)split * NMB + mb) * 2 + ns) * 64 + lane) * 16;
        #pragma unroll
        for (int r4 = 0; r4 < 4; ++r4) {
            const f32x4 v = *(const f32x4*)&redbuf[ns][lane][r4 * 4];
            f32x4 o;
            o.x = acc[r4 * 4 + 0] + v.x; o.y = acc[r4 * 4 + 1] + v.y;
            o.z = acc[r4 * 4 + 2] + v.z; o.w = acc[r4 * 4 + 3] + v.w;
            *(f32x4*)(pdst + r4 * 4) = o;
        }
    }
}

// ------------- sum KSPLIT partials + bias + SiLU (writes out once) -------------
__global__ __launch_bounds__(256) void finish_reduce(const float* __restrict__ part,
                                                     const float* __restrict__ b3,
                                                     float* __restrict__ out) {
    const int tid  = blockIdx.x * 256 + threadIdx.x;   // 65536 threads x 4 outputs
    const int rq   = tid & 3;
    const int lane = (tid >> 2) & 63;
    const int ns   = (tid >> 8) & 1;
    const int mb   = tid >> 9;
    const float* src = part + (((size_t)mb * 2 + ns) * 64 + lane) * 16 + rq * 4;
    f32x4 s = {0.f, 0.f, 0.f, 0.f};
    #pragma unroll
    for (int split = 0; split < KSPLIT; ++split) {
        const f32x4 v = *(const f32x4*)(src + (size_t)split * SPLIT_STRIDE);
        s.x += v.x; s.y += v.y; s.z += v.z; s.w += v.w;
    }
    const int col  = (ns << 5) + (lane & 31);   // d_out
    const float bias = b3[col];
    #pragma unroll
    for (int j = 0; j < 4; ++j) {
        // verified 32x32 C/D layout: row=(r&3)+8*(r>>2)+4*(lane>>5), col=lane&31
        const int prow = j + 8 * rq + 4 * (lane >> 5);
        out[(size_t)(mb * 32 + prow) * DD + col] = silu_f(s[j] + bias);
    }
}

extern "C" void kernel_launch(void* const* d_in, const int* in_sizes, int n_in,
                              void* d_out, int out_size, void* d_ws, size_t ws_size,
                              hipStream_t stream) {
    // inputs: x, start_L, idx_C, W1, b1, W2(unused), b2(unused), W3, b3
    const float* x       = (const float*)d_in[0];
    const int*   start_L = (const int*)  d_in[1];
    const int*   idx_C   = (const int*)  d_in[2];
    const float* W1      = (const float*)d_in[3];
    const float* b1      = (const float*)d_in[4];
    const float* W3      = (const float*)d_in[7];
    const float* b3      = (const float*)d_in[8];
    float* out  = (float*)d_out;
    u32*   wsf  = (u32*)d_ws;
    float* part = (float*)(wsf + FRAG_U32);

    w3_prep<<<256, 256, 0, stream>>>(W3, wsf);
    htfe_main<<<NMB * KSPLIT, NT_MAIN, 0, stream>>>(x, start_L, idx_C, W1, b1, wsf, part);
    finish_reduce<<<256, 256, 0, stream>>>(part, b3, out);
}

// Round 8
// 38.304 us; speedup vs baseline: 1.0503x; 1.0503x over previous
//
#include <hip/hip_runtime.h>
#include <hip/hip_bf16.h>

// Problem constants
#define BB 64
#define LL 4096
#define CC 16
#define PL 128
#define PC 8
#define NPP 64
#define DD 64
#define TSTEP 0.01f

#define KSPLIT 16                   // lt-range split across blocks
#define LT_PER (PL / KSPLIT)        // 8 lt steps per block
#define NT_MAIN 256                 // 4 waves = 2 kk-halves x 2 patch-halves
#define NMB BB                      // one block-column per batch (64 patches)

#define FRAG_U32 (PL * 8 * 256)                       // 1 MB of W3 bf16 frags
#define SPLIT_STRIDE (NMB * 2 * 2 * 64 * 16)          // 262144 floats per split
#define PART_FLT (KSPLIT * SPLIT_STRIDE)              // 16 MB of f32 partials

typedef float f32x4  __attribute__((ext_vector_type(4)));
typedef float f32x16 __attribute__((ext_vector_type(16)));
typedef int   i32x4  __attribute__((ext_vector_type(4)));
typedef short s16x8  __attribute__((ext_vector_type(8)));
typedef unsigned int u32;

__device__ __forceinline__ u32 f2bf(float f) {          // fp32 -> bf16 bits, RNE
    u32 u = __float_as_uint(f);
    return (u + 0x7fffu + ((u >> 16) & 1u)) >> 16;
}
__device__ __forceinline__ float silu_f(float z) {      // z * rcp(1+exp(-z))
    return z * __builtin_amdgcn_rcpf(1.0f + __expf(-z));
}
__device__ __forceinline__ u32 pk(float lo, float hi) {
    __hip_bfloat162 p = __float22bfloat162_rn(float2{lo, hi});
    u32 r;
    __builtin_memcpy(&r, &p, 4);
    return r;
}
__device__ __forceinline__ s16x8 as8(i32x4 v) {
    s16x8 r;
    __builtin_memcpy(&r, &v, 16);
    return r;
}
// exchange: a keeps lo-half, gets b's lo into its hi; b gets a's old hi into its lo
__device__ __forceinline__ void plswap(u32& a, u32& b) {
    auto r = __builtin_amdgcn_permlane32_swap(a, b, false, false);
    u32 tmp[2];
    __builtin_memcpy(tmp, &r, 8);
    a = tmp[0]; b = tmp[1];
}

// ---- W3 (8192x64 f32) -> bf16 frags for mfma_32x32x16, in ws (1 MB) ----
// frag m = ltg*8 + kk*4 + ksub*2 + ns ; lane holds W3[k0 + 2j(+1)][ns*32 + (l&31)]
__global__ __launch_bounds__(256) void w3_prep(const float* __restrict__ W3,
                                               u32* __restrict__ wsf) {
    const int tid  = blockIdx.x * 256 + threadIdx.x;    // 65536 threads
    const int lane = tid & 63;
    const int m    = tid >> 6;                          // 0..1023
    const int ns   = m & 1;
    const int ksub = (m >> 1) & 1;
    const int kk   = (m >> 2) & 1;
    const int ltg  = m >> 3;
    const int k0   = ltg * 64 + kk * 32 + ksub * 16 + ((lane >> 5) << 3);
    const int col  = (ns << 5) + (lane & 31);
    u32 q[4];
    #pragma unroll
    for (int jj = 0; jj < 4; ++jj)
        q[jj] = pk(W3[(size_t)(k0 + 2 * jj)     * DD + col],
                   W3[(size_t)(k0 + 2 * jj + 1) * DD + col]);
    i32x4 v; v.x = (int)q[0]; v.y = (int)q[1]; v.z = (int)q[2]; v.w = (int)q[3];
    *(i32x4*)(wsf + (size_t)m * 256 + (lane << 2)) = v;
}

// ---------------------------- fused main kernel ----------------------------
// GEMM1 (feats@W1, K=17 padded to 32) runs on MFMA with swapped operands:
//   hpre[d'][p] = sum_k W1[k][kk*32+d'] * feats[k][p]
// K-slot map: 0-7 = x_hi, 8 = (unused, folded), 9-16 -> moved:
//   frag0: k0-7 = x_hi (B lo lanes), k8-15 = c0..c7 (B hi lanes, registers)
//   frag1: k16 = t_hi, k17 = t_lo (same W1[8] weight), k18 = bias (B=1),
//          k24-31 = x_lo (weights W1[0..7] again)  -> f32-accurate t and x.
// hpre fragment -> GEMM2 A-frag via 8 cvt_pk + 4 permlane32_swap (no LDS, no
// barrier in the lt loop). NOTE: no min-waves hint (round 4: forced spills).
__global__ __launch_bounds__(NT_MAIN) void htfe_main(
    const float* __restrict__ x, const int* __restrict__ start_L,
    const int* __restrict__ idx_C, const float* __restrict__ W1,
    const float* __restrict__ b1, const u32* __restrict__ wsf,
    float* __restrict__ part)
{
    __shared__ __align__(16) u32    xqf[LT_PER * 64 * 8];   // 16 KB x_hi/x_lo packs
    __shared__ __align__(16) f32x16 redacc[2][2][64];       // 16 KB kk-reduction
    __shared__ int sStart[64];
    __shared__ int sCi[64][PC];

    const int t    = threadIdx.x;
    const int lane = t & 63;
    const int w    = t >> 6;
    const int kk   = w >> 1;                 // K-half of each lt's 64 k
    const int ph   = w & 1;                  // patch half
    const int l31  = lane & 31;
    const bool loH = lane < 32;

    const int mb    = blockIdx.x & (NMB - 1);   // = batch b
    const int split = blockIdx.x >> 6;
    const int b     = mb;
    const int lt0   = split * LT_PER;

    if (t < 64) sStart[t] = start_L[b * NPP + t];
    {
        const int i0 = t, i1 = t + 256;
        sCi[i0 >> 3][i0 & 7] = idx_C[(size_t)b * NPP * PC + i0];
        sCi[i1 >> 3][i1 & 7] = idx_C[(size_t)b * NPP * PC + i1];
    }
    __syncthreads();

    const int p  = ph * 32 + l31;            // patch this lane owns
    const int dA = kk * 32 + l31;            // d' row this lane owns in GEMM1
    const float startPf = (float)sStart[p];

    // ----- GEMM1 A-fragments (W1^T slices), built once -----
    i32x4 a1f0, a1f1;
    if (loH) {   // k=0..7: x_hi weights          k=16..18: t_hi,t_lo,bias
        a1f0.x = (int)pk(W1[0 * DD + dA], W1[1 * DD + dA]);
        a1f0.y = (int)pk(W1[2 * DD + dA], W1[3 * DD + dA]);
        a1f0.z = (int)pk(W1[4 * DD + dA], W1[5 * DD + dA]);
        a1f0.w = (int)pk(W1[6 * DD + dA], W1[7 * DD + dA]);
        a1f1.x = (int)pk(W1[8 * DD + dA], W1[8 * DD + dA]);
        a1f1.y = (int)pk(b1[dA], 0.0f);
        a1f1.z = 0; a1f1.w = 0;
    } else {     // k=8..15: c weights (rows 9..16)   k=24..31: x_lo weights
        a1f0.x = (int)pk(W1[ 9 * DD + dA], W1[10 * DD + dA]);
        a1f0.y = (int)pk(W1[11 * DD + dA], W1[12 * DD + dA]);
        a1f0.z = (int)pk(W1[13 * DD + dA], W1[14 * DD + dA]);
        a1f0.w = (int)pk(W1[15 * DD + dA], W1[16 * DD + dA]);
        a1f1.x = (int)pk(W1[0 * DD + dA], W1[1 * DD + dA]);
        a1f1.y = (int)pk(W1[2 * DD + dA], W1[3 * DD + dA]);
        a1f1.z = (int)pk(W1[4 * DD + dA], W1[5 * DD + dA]);
        a1f1.w = (int)pk(W1[6 * DD + dA], W1[7 * DD + dA]);
    }
    // c-feature B-frag half (lt-invariant, registers)
    i32x4 cReg;
    cReg.x = (int)pk((float)sCi[p][0], (float)sCi[p][1]);
    cReg.y = (int)pk((float)sCi[p][2], (float)sCi[p][3]);
    cReg.z = (int)pk((float)sCi[p][4], (float)sCi[p][5]);
    cReg.w = (int)pk((float)sCi[p][6], (float)sCi[p][7]);

    // ----- gather x, split hi/lo bf16, swizzled store (banks spread) -----
    #pragma unroll
    for (int uu = 0; uu < 2; ++uu) {
        const int u  = t * 2 + uu;           // 512 (lt,p) units
        const int lt = u >> 6;
        const int pp = u & 63;
        const float* xrow = x + ((size_t)b * LL + (size_t)(sStart[pp] + lt0 + lt)) * CC;
        u32 qh[4], ql[4];
        #pragma unroll
        for (int c2 = 0; c2 < 4; ++c2) {
            const float v0 = xrow[sCi[pp][2 * c2]];
            const float v1 = xrow[sCi[pp][2 * c2 + 1]];
            const u32 h0 = f2bf(v0), h1 = f2bf(v1);
            qh[c2] = h0 | (h1 << 16);
            ql[c2] = f2bf(v0 - __uint_as_float(h0 << 16)) |
                     (f2bf(v1 - __uint_as_float(h1 << 16)) << 16);
        }
        const int swz = ((pp >> 2) & 1) << 2;
        u32* dst = xqf + lt * 512 + pp * 8;
        i32x4 vh; vh.x=(int)qh[0]; vh.y=(int)qh[1]; vh.z=(int)qh[2]; vh.w=(int)qh[3];
        i32x4 vl; vl.x=(int)ql[0]; vl.y=(int)ql[1]; vl.z=(int)ql[2]; vl.w=(int)ql[3];
        *(i32x4*)(dst + (0 ^ swz)) = vh;
        *(i32x4*)(dst + (4 ^ swz)) = vl;
    }
    __syncthreads();

    // ----- main loop: no barriers, no h LDS buffer -----
    f32x16 acc0 = {}, acc1 = {};
    const u32* bsrc = wsf + ((size_t)lt0 * 8 + (size_t)kk * 4) * 256 + (lane << 2);
    const u32 ONEP = pk(1.0f, 0.0f);
    // lo lanes read x_hi (half 0), hi lanes read x_lo (half 1), same swizzle
    const u32* xrd = xqf + p * 8 + ((((lane >> 5) << 2) ^ (((p >> 2) & 1) << 2)));

    #pragma unroll 2
    for (int lt = 0; lt < LT_PER; ++lt) {
        // W3 B-frags (L2-resident workspace)
        const i32x4 bf00 = *(const i32x4*)(bsrc);         // ksub0 ns0
        const i32x4 bf01 = *(const i32x4*)(bsrc + 256);   // ksub0 ns1
        const i32x4 bf10 = *(const i32x4*)(bsrc + 512);   // ksub1 ns0
        const i32x4 bf11 = *(const i32x4*)(bsrc + 768);   // ksub1 ns1
        bsrc += 2048;

        const i32x4 rd = *(const i32x4*)(xrd + lt * 512);

        // t feature, split into bf16 hi+lo for f32 accuracy
        const float tf  = (startPf + (float)(lt0 + lt)) * TSTEP;
        const u32   tb  = f2bf(tf);
        const u32   tpk2 = tb | (f2bf(tf - __uint_as_float(tb << 16)) << 16);
        i32x4 tvec; tvec.x = (int)tpk2; tvec.y = (int)ONEP; tvec.z = 0; tvec.w = 0;

        const i32x4 b0f = loH ? rd : cReg;    // frag0: x_hi | c
        const i32x4 b1f = loH ? tvec : rd;    // frag1: t/bias | x_lo

        // GEMM1: hpre[d'][p]
        f32x16 hp = {};
        hp = __builtin_amdgcn_mfma_f32_32x32x16_bf16(as8(a1f0), as8(b0f), hp, 0, 0, 0);
        hp = __builtin_amdgcn_mfma_f32_32x32x16_bf16(as8(a1f1), as8(b1f), hp, 0, 0, 0);

        // silu + pack to bf16 pairs (P[j] = rows (2j,2j+1) of this lane's quads)
        u32 P[8];
        #pragma unroll
        for (int j = 0; j < 8; ++j)
            P[j] = pk(silu_f(hp[2 * j]), silu_f(hp[2 * j + 1]));

        // fragment exchange: hpre C/D layout -> GEMM2 A-frag layout
        plswap(P[0], P[2]); plswap(P[1], P[3]);   // af0 = {P0,P1,P2,P3}
        plswap(P[4], P[6]); plswap(P[5], P[7]);   // af1 = {P4,P5,P6,P7}
        i32x4 af0; af0.x=(int)P[0]; af0.y=(int)P[1]; af0.z=(int)P[2]; af0.w=(int)P[3];
        i32x4 af1; af1.x=(int)P[4]; af1.y=(int)P[5]; af1.z=(int)P[6]; af1.w=(int)P[7];

        // GEMM2: accumulate both ns slices
        acc0 = __builtin_amdgcn_mfma_f32_32x32x16_bf16(as8(af0), as8(bf00), acc0, 0, 0, 0);
        acc0 = __builtin_amdgcn_mfma_f32_32x32x16_bf16(as8(af1), as8(bf10), acc0, 0, 0, 0);
        acc1 = __builtin_amdgcn_mfma_f32_32x32x16_bf16(as8(af0), as8(bf01), acc1, 0, 0, 0);
        acc1 = __builtin_amdgcn_mfma_f32_32x32x16_bf16(as8(af1), as8(bf11), acc1, 0, 0, 0);
    }

    // ----- kk-reduction in LDS, then one coalesced partial store -----
    if (kk == 1) {
        redacc[ph][0][lane] = acc0;
        redacc[ph][1][lane] = acc1;
    }
    __syncthreads();
    if (kk == 0) {
        const f32x16 r0 = redacc[ph][0][lane];
        const f32x16 r1 = redacc[ph][1][lane];
        float* pd0 = part + ((((size_t)split * NMB + mb) * 2 + ph) * 2 + 0) * 1024 + (lane << 4);
        float* pd1 = pd0 + 1024;
        #pragma unroll
        for (int q = 0; q < 4; ++q) {
            f32x4 o0, o1;
            #pragma unroll
            for (int j = 0; j < 4; ++j) {
                o0[j] = acc0[q * 4 + j] + r0[q * 4 + j];
                o1[j] = acc1[q * 4 + j] + r1[q * 4 + j];
            }
            *(f32x4*)(pd0 + q * 4) = o0;
            *(f32x4*)(pd1 + q * 4) = o1;
        }
    }
}

// ------------- sum KSPLIT partials + bias + SiLU (writes out once) -------------
__global__ __launch_bounds__(256) void finish_reduce(const float* __restrict__ part,
                                                     const float* __restrict__ b3,
                                                     float* __restrict__ out) {
    const int tid  = blockIdx.x * 256 + threadIdx.x;   // 65536 threads x 4 outputs
    const int rq   = tid & 3;
    const int lane = (tid >> 2) & 63;
    const int ns   = (tid >> 8) & 1;
    const int ph   = (tid >> 9) & 1;
    const int mb   = tid >> 10;
    const int l31  = lane & 31;
    const float* src = part + (((size_t)mb * 2 + ph) * 2 + ns) * 1024 + (lane << 4) + (rq << 2);
    f32x4 s = {0.f, 0.f, 0.f, 0.f};
    #pragma unroll
    for (int sp = 0; sp < KSPLIT; ++sp) {
        const f32x4 v = *(const f32x4*)(src + (size_t)sp * SPLIT_STRIDE);
        s.x += v.x; s.y += v.y; s.z += v.z; s.w += v.w;
    }
    const int col  = (ns << 5) + l31;
    const float bias = b3[col];
    #pragma unroll
    for (int j = 0; j < 4; ++j) {
        // verified 32x32 C/D layout: row=(r&3)+8*(r>>2)+4*(lane>>5), col=lane&31
        const int prow = ph * 32 + j + 8 * rq + 4 * (lane >> 5);
        out[((size_t)mb * NPP + prow) * DD + col] = silu_f(s[j] + bias);
    }
}

extern "C" void kernel_launch(void* const* d_in, const int* in_sizes, int n_in,
                              void* d_out, int out_size, void* d_ws, size_t ws_size,
                              hipStream_t stream) {
    // inputs: x, start_L, idx_C, W1, b1, W2(unused), b2(unused), W3, b3
    const float* x       = (const float*)d_in[0];
    const int*   start_L = (const int*)  d_in[1];
    const int*   idx_C   = (const int*)  d_in[2];
    const float* W1      = (const float*)d_in[3];
    const float* b1      = (const float*)d_in[4];
    const float* W3      = (const float*)d_in[7];
    const float* b3      = (const float*)d_in[8];
    float* out  = (float*)d_out;
    u32*   wsf  = (u32*)d_ws;
    float* part = (float*)(wsf + FRAG_U32);

    w3_prep<<<256, 256, 0, stream>>>(W3, wsf);
    htfe_main<<<NMB * KSPLIT, NT_MAIN, 0, stream>>>(x, start_L, idx_C, W1, b1, wsf, part);
    finish_reduce<<<256, 256, 0, stream>>>(part, b3, out);
}

// Round 9
// 36.369 us; speedup vs baseline: 1.1062x; 1.0532x over previous
//
#include <hip/hip_runtime.h>
#include <hip/hip_bf16.h>

// Problem constants
#define BB 64
#define LL 4096
#define CC 16
#define PL 128
#define PC 8
#define NPP 64
#define DD 64
#define TSTEP 0.01f

#define KSPLIT 16                   // lt-range split across blocks
#define LT_PER (PL / KSPLIT)        // 8 lt steps per block
#define NT_MAIN 256                 // 4 waves = 2 kk-halves x 2 patch-halves
#define NMB BB                      // one block-column per batch (64 patches)

#define FRAG_U32 (PL * 8 * 256)                       // 1 MB of W3 bf16 frags
#define SPLIT_STRIDE (NMB * 2 * 2 * 64 * 16)          // 262144 floats per split
#define PART_FLT (KSPLIT * SPLIT_STRIDE)              // 16 MB of f32 partials

typedef float f32x4  __attribute__((ext_vector_type(4)));
typedef float f32x16 __attribute__((ext_vector_type(16)));
typedef int   i32x4  __attribute__((ext_vector_type(4)));
typedef short s16x8  __attribute__((ext_vector_type(8)));
typedef unsigned int u32;

__device__ __forceinline__ u32 f2bf(float f) {          // fp32 -> bf16 bits, RNE
    u32 u = __float_as_uint(f);
    return (u + 0x7fffu + ((u >> 16) & 1u)) >> 16;
}
__device__ __forceinline__ float silu_f(float z) {      // z * rcp(1+exp(-z))
    return z * __builtin_amdgcn_rcpf(1.0f + __expf(-z));
}
__device__ __forceinline__ u32 pk(float lo, float hi) {
    __hip_bfloat162 p = __float22bfloat162_rn(float2{lo, hi});
    u32 r;
    __builtin_memcpy(&r, &p, 4);
    return r;
}
__device__ __forceinline__ s16x8 as8(i32x4 v) {
    s16x8 r;
    __builtin_memcpy(&r, &v, 16);
    return r;
}
// exchange: a keeps lo-half, gets b's lo into its hi; b gets a's old hi into its lo
__device__ __forceinline__ void plswap(u32& a, u32& b) {
    auto r = __builtin_amdgcn_permlane32_swap(a, b, false, false);
    u32 tmp[2];
    __builtin_memcpy(tmp, &r, 8);
    a = tmp[0]; b = tmp[1];
}

// ---- W3 (8192x64 f32) -> bf16 frags for mfma_32x32x16, in ws (1 MB) ----
// frag m = ltg*8 + kk*4 + ksub*2 + ns ; lane holds W3[k0 + 2j(+1)][ns*32 + (l&31)]
__global__ __launch_bounds__(256) void w3_prep(const float* __restrict__ W3,
                                               u32* __restrict__ wsf) {
    const int tid  = blockIdx.x * 256 + threadIdx.x;    // 65536 threads
    const int lane = tid & 63;
    const int m    = tid >> 6;                          // 0..1023
    const int ns   = m & 1;
    const int ksub = (m >> 1) & 1;
    const int kk   = (m >> 2) & 1;
    const int ltg  = m >> 3;
    const int k0   = ltg * 64 + kk * 32 + ksub * 16 + ((lane >> 5) << 3);
    const int col  = (ns << 5) + (lane & 31);
    u32 q[4];
    #pragma unroll
    for (int jj = 0; jj < 4; ++jj)
        q[jj] = pk(W3[(size_t)(k0 + 2 * jj)     * DD + col],
                   W3[(size_t)(k0 + 2 * jj + 1) * DD + col]);
    i32x4 v; v.x = (int)q[0]; v.y = (int)q[1]; v.z = (int)q[2]; v.w = (int)q[3];
    *(i32x4*)(wsf + (size_t)m * 256 + (lane << 2)) = v;
}

// ---------------------------- fused main kernel ----------------------------
// GEMM1 (feats@W1, K padded to 32) on MFMA with swapped operands (round 8,
// verified). This round: coalesced row staging (vector row loads -> LDS
// rowbuf -> LDS channel-gather) replacing the 16 divergent scalar gathers,
// and conflict-free xqf layout [lt][half][p][4].
// NOTE: no min-waves hint (round 4: forced spills).
__global__ __launch_bounds__(NT_MAIN) void htfe_main(
    const float* __restrict__ x, const int* __restrict__ start_L,
    const int* __restrict__ idx_C, const float* __restrict__ W1,
    const float* __restrict__ b1, const u32* __restrict__ wsf,
    float* __restrict__ part)
{
    // arena: rowbuf (256 rows x 17 f32 = 17408 B) during staging,
    //        kk-reduction accumulators (16384 B) after the main loop.
    __shared__ __align__(64) float arena[256 * 17];
    __shared__ __align__(16) u32   xqf[LT_PER * 512];    // [lt][half][64 p][4]
    __shared__ int sStart[64];
    __shared__ int sCi[64][PC];

    const int t    = threadIdx.x;
    const int lane = t & 63;
    const int w    = t >> 6;
    const int kk   = w >> 1;                 // K-half of each lt's 64 k
    const int ph   = w & 1;                  // patch half
    const int l31  = lane & 31;
    const bool loH = lane < 32;

    const int mb    = blockIdx.x & (NMB - 1);   // = batch b; XCD = mb%8 for all splits
    const int split = blockIdx.x >> 6;
    const int b     = mb;
    const int lt0   = split * LT_PER;

    if (t < 64) sStart[t] = start_L[b * NPP + t];
    {
        const int i0 = t, i1 = t + 256;
        sCi[i0 >> 3][i0 & 7] = idx_C[(size_t)b * NPP * PC + i0];
        sCi[i1 >> 3][i1 & 7] = idx_C[(size_t)b * NPP * PC + i1];
    }
    // gather thread's channel indices straight from global (coalesced, L2)
    const int pGat = t & 63;
    const i32x4 ciA = *(const i32x4*)(idx_C + (size_t)b * NPP * PC + pGat * 8);
    const i32x4 ciB = *(const i32x4*)(idx_C + (size_t)b * NPP * PC + pGat * 8 + 4);
    __syncthreads();

    // ----- staging: 2 passes x 256 rows; coalesced row loads -> LDS gather -----
    #pragma unroll
    for (int pass = 0; pass < 2; ++pass) {
        #pragma unroll
        for (int q = 0; q < 4; ++q) {
            const int i    = q * 256 + t;       // 1024 float4 units
            const int row  = i >> 2;            // 0..255
            const int quad = i & 3;
            const int pp   = row & 63;
            const int gRow = sStart[pp] + lt0 + pass * 4 + (row >> 6);
            const f32x4 v = *(const f32x4*)(x + ((size_t)b * LL + (size_t)gRow) * CC + quad * 4);
            *(f32x4*)(arena + row * 17 + quad * 4) = v;
        }
        __syncthreads();
        {   // gather own row r = t: 8 LDS reads (stride-17 -> conflict-free)
            const float* rb = arena + t * 17;
            int cis[8];
            cis[0]=ciA.x; cis[1]=ciA.y; cis[2]=ciA.z; cis[3]=ciA.w;
            cis[4]=ciB.x; cis[5]=ciB.y; cis[6]=ciB.z; cis[7]=ciB.w;
            u32 qh[4], ql[4];
            #pragma unroll
            for (int c2 = 0; c2 < 4; ++c2) {
                const float v0 = rb[cis[2 * c2]];
                const float v1 = rb[cis[2 * c2 + 1]];
                const u32 h0 = f2bf(v0), h1 = f2bf(v1);
                qh[c2] = h0 | (h1 << 16);
                ql[c2] = f2bf(v0 - __uint_as_float(h0 << 16)) |
                         (f2bf(v1 - __uint_as_float(h1 << 16)) << 16);
            }
            u32* dst = xqf + (pass * 4 + (t >> 6)) * 512 + pGat * 4;
            i32x4 vh; vh.x=(int)qh[0]; vh.y=(int)qh[1]; vh.z=(int)qh[2]; vh.w=(int)qh[3];
            i32x4 vl; vl.x=(int)ql[0]; vl.y=(int)ql[1]; vl.z=(int)ql[2]; vl.w=(int)ql[3];
            *(i32x4*)(dst)       = vh;   // half 0: x_hi
            *(i32x4*)(dst + 256) = vl;   // half 1: x_lo
        }
        __syncthreads();
    }

    const int p  = ph * 32 + l31;            // patch this lane owns
    const int dA = kk * 32 + l31;            // d' row this lane owns in GEMM1
    const float startPf = (float)sStart[p];

    // ----- GEMM1 A-fragments (W1^T slices), built once -----
    i32x4 a1f0, a1f1;
    if (loH) {   // k=0..7: x_hi weights          k=16..18: t_hi,t_lo,bias
        a1f0.x = (int)pk(W1[0 * DD + dA], W1[1 * DD + dA]);
        a1f0.y = (int)pk(W1[2 * DD + dA], W1[3 * DD + dA]);
        a1f0.z = (int)pk(W1[4 * DD + dA], W1[5 * DD + dA]);
        a1f0.w = (int)pk(W1[6 * DD + dA], W1[7 * DD + dA]);
        a1f1.x = (int)pk(W1[8 * DD + dA], W1[8 * DD + dA]);
        a1f1.y = (int)pk(b1[dA], 0.0f);
        a1f1.z = 0; a1f1.w = 0;
    } else {     // k=8..15: c weights (rows 9..16)   k=24..31: x_lo weights
        a1f0.x = (int)pk(W1[ 9 * DD + dA], W1[10 * DD + dA]);
        a1f0.y = (int)pk(W1[11 * DD + dA], W1[12 * DD + dA]);
        a1f0.z = (int)pk(W1[13 * DD + dA], W1[14 * DD + dA]);
        a1f0.w = (int)pk(W1[15 * DD + dA], W1[16 * DD + dA]);
        a1f1.x = (int)pk(W1[0 * DD + dA], W1[1 * DD + dA]);
        a1f1.y = (int)pk(W1[2 * DD + dA], W1[3 * DD + dA]);
        a1f1.z = (int)pk(W1[4 * DD + dA], W1[5 * DD + dA]);
        a1f1.w = (int)pk(W1[6 * DD + dA], W1[7 * DD + dA]);
    }
    // c-feature B-frag half (lt-invariant, registers)
    i32x4 cReg;
    cReg.x = (int)pk((float)sCi[p][0], (float)sCi[p][1]);
    cReg.y = (int)pk((float)sCi[p][2], (float)sCi[p][3]);
    cReg.z = (int)pk((float)sCi[p][4], (float)sCi[p][5]);
    cReg.w = (int)pk((float)sCi[p][6], (float)sCi[p][7]);

    // ----- main loop: no barriers, no h LDS buffer -----
    f32x16 acc0 = {}, acc1 = {};
    const u32* bsrc = wsf + ((size_t)lt0 * 8 + (size_t)kk * 4) * 256 + (lane << 2);
    const u32 ONEP = pk(1.0f, 0.0f);
    // lo lanes read x_hi (half 0), hi lanes read x_lo (half 1); conflict-free layout
    const u32* xrd = xqf + ((lane >> 5) << 8) + (p << 2);

    #pragma unroll 2
    for (int lt = 0; lt < LT_PER; ++lt) {
        // W3 B-frags (L2-resident workspace)
        const i32x4 bf00 = *(const i32x4*)(bsrc);         // ksub0 ns0
        const i32x4 bf01 = *(const i32x4*)(bsrc + 256);   // ksub0 ns1
        const i32x4 bf10 = *(const i32x4*)(bsrc + 512);   // ksub1 ns0
        const i32x4 bf11 = *(const i32x4*)(bsrc + 768);   // ksub1 ns1
        bsrc += 2048;

        const i32x4 rd = *(const i32x4*)(xrd + lt * 512);

        // t feature, split into bf16 hi+lo for f32 accuracy
        const float tf  = (startPf + (float)(lt0 + lt)) * TSTEP;
        const u32   tb  = f2bf(tf);
        const u32   tpk2 = tb | (f2bf(tf - __uint_as_float(tb << 16)) << 16);
        i32x4 tvec; tvec.x = (int)tpk2; tvec.y = (int)ONEP; tvec.z = 0; tvec.w = 0;

        const i32x4 b0f = loH ? rd : cReg;    // frag0: x_hi | c
        const i32x4 b1f = loH ? tvec : rd;    // frag1: t/bias | x_lo

        // GEMM1: hpre[d'][p]
        f32x16 hp = {};
        hp = __builtin_amdgcn_mfma_f32_32x32x16_bf16(as8(a1f0), as8(b0f), hp, 0, 0, 0);
        hp = __builtin_amdgcn_mfma_f32_32x32x16_bf16(as8(a1f1), as8(b1f), hp, 0, 0, 0);

        // silu + pack to bf16 pairs (P[j] = rows (2j,2j+1) of this lane's quads)
        u32 P[8];
        #pragma unroll
        for (int j = 0; j < 8; ++j)
            P[j] = pk(silu_f(hp[2 * j]), silu_f(hp[2 * j + 1]));

        // fragment exchange: hpre C/D layout -> GEMM2 A-frag layout
        plswap(P[0], P[2]); plswap(P[1], P[3]);   // af0 = {P0,P1,P2,P3}
        plswap(P[4], P[6]); plswap(P[5], P[7]);   // af1 = {P4,P5,P6,P7}
        i32x4 af0; af0.x=(int)P[0]; af0.y=(int)P[1]; af0.z=(int)P[2]; af0.w=(int)P[3];
        i32x4 af1; af1.x=(int)P[4]; af1.y=(int)P[5]; af1.z=(int)P[6]; af1.w=(int)P[7];

        // GEMM2: accumulate both ns slices
        acc0 = __builtin_amdgcn_mfma_f32_32x32x16_bf16(as8(af0), as8(bf00), acc0, 0, 0, 0);
        acc0 = __builtin_amdgcn_mfma_f32_32x32x16_bf16(as8(af1), as8(bf10), acc0, 0, 0, 0);
        acc1 = __builtin_amdgcn_mfma_f32_32x32x16_bf16(as8(af0), as8(bf01), acc1, 0, 0, 0);
        acc1 = __builtin_amdgcn_mfma_f32_32x32x16_bf16(as8(af1), as8(bf11), acc1, 0, 0, 0);
    }

    // ----- kk-reduction in LDS (arena reused), then one coalesced partial store -----
    f32x16* redacc = (f32x16*)arena;    // [ph][2][64]
    __syncthreads();                    // all rowbuf use long done; re-purpose arena
    if (kk == 1) {
        redacc[(ph * 2 + 0) * 64 + lane] = acc0;
        redacc[(ph * 2 + 1) * 64 + lane] = acc1;
    }
    __syncthreads();
    if (kk == 0) {
        const f32x16 r0 = redacc[(ph * 2 + 0) * 64 + lane];
        const f32x16 r1 = redacc[(ph * 2 + 1) * 64 + lane];
        float* pd0 = part + ((((size_t)split * NMB + mb) * 2 + ph) * 2 + 0) * 1024 + (lane << 4);
        float* pd1 = pd0 + 1024;
        #pragma unroll
        for (int q = 0; q < 4; ++q) {
            f32x4 o0, o1;
            #pragma unroll
            for (int j = 0; j < 4; ++j) {
                o0[j] = acc0[q * 4 + j] + r0[q * 4 + j];
                o1[j] = acc1[q * 4 + j] + r1[q * 4 + j];
            }
            *(f32x4*)(pd0 + q * 4) = o0;
            *(f32x4*)(pd1 + q * 4) = o1;
        }
    }
}

// ------------- sum KSPLIT partials + bias + SiLU (writes out once) -------------
// Block bid handles mb = bid & 63 -> bid%8 == mb%8 == writer XCD (L2-resident read).
__global__ __launch_bounds__(256) void finish_reduce(const float* __restrict__ part,
                                                     const float* __restrict__ b3,
                                                     float* __restrict__ out) {
    const int bid   = blockIdx.x;            // 256
    const int mb    = bid & 63;
    const int chunk = bid >> 6;              // 0..3
    const int idx10 = chunk * 256 + threadIdx.x;   // 0..1023 within mb
    const int rq   = idx10 & 3;
    const int lane = (idx10 >> 2) & 63;
    const int ns   = (idx10 >> 8) & 1;
    const int ph   = (idx10 >> 9) & 1;
    const int l31  = lane & 31;
    const float* src = part + (((size_t)mb * 2 + ph) * 2 + ns) * 1024 + (lane << 4) + (rq << 2);
    f32x4 s = {0.f, 0.f, 0.f, 0.f};
    #pragma unroll
    for (int sp = 0; sp < KSPLIT; ++sp) {
        const f32x4 v = *(const f32x4*)(src + (size_t)sp * SPLIT_STRIDE);
        s.x += v.x; s.y += v.y; s.z += v.z; s.w += v.w;
    }
    const int col  = (ns << 5) + l31;
    const float bias = b3[col];
    #pragma unroll
    for (int j = 0; j < 4; ++j) {
        // verified 32x32 C/D layout: row=(r&3)+8*(r>>2)+4*(lane>>5), col=lane&31
        const int prow = ph * 32 + j + 8 * rq + 4 * (lane >> 5);
        out[((size_t)mb * NPP + prow) * DD + col] = silu_f(s[j] + bias);
    }
}

extern "C" void kernel_launch(void* const* d_in, const int* in_sizes, int n_in,
                              void* d_out, int out_size, void* d_ws, size_t ws_size,
                              hipStream_t stream) {
    // inputs: x, start_L, idx_C, W1, b1, W2(unused), b2(unused), W3, b3
    const float* x       = (const float*)d_in[0];
    const int*   start_L = (const int*)  d_in[1];
    const int*   idx_C   = (const int*)  d_in[2];
    const float* W1      = (const float*)d_in[3];
    const float* b1      = (const float*)d_in[4];
    const float* W3      = (const float*)d_in[7];
    const float* b3      = (const float*)d_in[8];
    float* out  = (float*)d_out;
    u32*   wsf  = (u32*)d_ws;
    float* part = (float*)(wsf + FRAG_U32);

    w3_prep<<<256, 256, 0, stream>>>(W3, wsf);
    htfe_main<<<NMB * KSPLIT, NT_MAIN, 0, stream>>>(x, start_L, idx_C, W1, b1, wsf, part);
    finish_reduce<<<256, 256, 0, stream>>>(part, b3, out);
}